// Round 1
// baseline (470.122 us; speedup 1.0000x reference)
//
#include <hip/hip_runtime.h>
#include <hip/hip_bf16.h>
#include <stdint.h>

#define M_DIM 8192
#define K_DIM 4096
#define N_DIM 4096

#define BM 128
#define BN 128
#define BK 64

typedef int v4i __attribute__((ext_vector_type(4)));

// ---------------------------------------------------------------------------
// Kernel 1: convert int32-stored int8 values -> packed int8 in ws, and copy
// scale_out into the tail of d_out.
// ---------------------------------------------------------------------------
__global__ void convert_pack_kernel(const int* __restrict__ A,
                                    const int* __restrict__ B,
                                    const float* __restrict__ scale_out,
                                    int8_t* __restrict__ A8,
                                    int8_t* __restrict__ B8,
                                    float* __restrict__ out_tail) {
  long gid = blockIdx.x * (long)blockDim.x + threadIdx.x;
  long stride = (long)gridDim.x * blockDim.x;

  // tail: scale_out passthrough (M floats)
  for (long i = gid; i < M_DIM; i += stride) out_tail[i] = scale_out[i];

  const long agran = (long)M_DIM * K_DIM / 16;   // 16 elems per granule
  const long total = (long)(M_DIM + N_DIM) * K_DIM / 16;
  for (long g = gid; g < total; g += stride) {
    const int4* src;
    int4* dst;
    if (g < agran) {
      src = ((const int4*)A) + g * 4;
      dst = ((int4*)A8) + g;
    } else {
      long h = g - agran;
      src = ((const int4*)B) + h * 4;
      dst = ((int4*)B8) + h;
    }
    int4 a = src[0], b = src[1], c = src[2], d = src[3];
    int4 o;
    o.x = (a.x & 255) | ((a.y & 255) << 8) | ((a.z & 255) << 16) | ((a.w & 255) << 24);
    o.y = (b.x & 255) | ((b.y & 255) << 8) | ((b.z & 255) << 16) | ((b.w & 255) << 24);
    o.z = (c.x & 255) | ((c.y & 255) << 8) | ((c.z & 255) << 16) | ((c.w & 255) << 24);
    o.w = (d.x & 255) | ((d.y & 255) << 8) | ((d.z & 255) << 16) | ((d.w & 255) << 24);
    dst[0] = o;
  }
}

// ---------------------------------------------------------------------------
// Kernel 2: i8 GEMM, m97 structure (128x128 tile, BK=64, 4 waves,
// global_load_lds width-16, XOR-swizzled LDS granules, mfma_i32_16x16x64_i8).
//
// LDS layout (per tile, A and B identical): 128 rows x 64 bytes, stored as
// 16B granules. Content k-group kg of row r lives at slot (kg ^ ((r>>1)&3)).
// The swizzle is applied on the GLOBAL source address during staging (LDS
// dest stays linear, as global_load_lds requires) and on the ds_read address
// (both-sides involution).
// ---------------------------------------------------------------------------
__global__ __launch_bounds__(256) void gemm_i8_kernel(
    const int8_t* __restrict__ A8, const int8_t* __restrict__ B8,
    const float* __restrict__ sA, const float* __restrict__ sB,
    const float* __restrict__ sO, float* __restrict__ out) {
  __shared__ int8_t lA[BM * BK];  // 8 KB
  __shared__ int8_t lB[BN * BK];  // 8 KB

  const int tid = threadIdx.x;
  const int wid = tid >> 6;
  const int lane = tid & 63;

  // XCD-aware bijective swizzle (nwg = 2048, divisible by 8)
  const int nwg = gridDim.x;
  const int cpx = nwg >> 3;
  const int bid = blockIdx.x;
  const int wg = (bid & 7) * cpx + (bid >> 3);
  const int tm = wg >> 5;   // M/BM = 64 row tiles, N/BN = 32 col tiles
  const int tn = wg & 31;
  const int row0 = tm * BM;
  const int col0 = tn * BN;

  // ---- staging setup: wave w issues instructions i = w and i = w+4 for each
  // of A and B. Instruction i stages granules g = i*64 + j (j = lane):
  //   row r = 16*i + (j>>2), content k-group = (j&3) ^ ((j>>3)&3).
  const int j = lane;
  const int koff = (((j & 3) ^ ((j >> 3) & 3)) << 4);
  const int r_lo = 16 * wid + (j >> 2);
  const int r_hi = r_lo + 64;

  const int8_t* pA0 = A8 + (size_t)(row0 + r_lo) * K_DIM + koff;
  const int8_t* pA1 = A8 + (size_t)(row0 + r_hi) * K_DIM + koff;
  const int8_t* pB0 = B8 + (size_t)(col0 + r_lo) * K_DIM + koff;
  const int8_t* pB1 = B8 + (size_t)(col0 + r_hi) * K_DIM + koff;

  int8_t* dA0 = lA + wid * 1024;
  int8_t* dA1 = lA + (wid + 4) * 1024;
  int8_t* dB0 = lB + wid * 1024;
  int8_t* dB1 = lB + (wid + 4) * 1024;

  // ---- fragment read offsets (swizzled ds_read_b128 addresses)
  const int fr = lane & 15;   // row/col within 16x16 fragment
  const int fk = lane >> 4;   // k-group (16 bytes each)
  const int wr = wid >> 1;    // wave row (0..1)
  const int wc = wid & 1;     // wave col (0..1)

  int aoff[4], boff[4];
#pragma unroll
  for (int m = 0; m < 4; ++m) {
    int r = wr * 64 + m * 16 + fr;
    aoff[m] = (r * 4 + (fk ^ ((r >> 1) & 3))) * 16;
  }
#pragma unroll
  for (int n = 0; n < 4; ++n) {
    int r = wc * 64 + n * 16 + fr;
    boff[n] = (r * 4 + (fk ^ ((r >> 1) & 3))) * 16;
  }

  v4i acc[4][4];
#pragma unroll
  for (int m = 0; m < 4; ++m)
#pragma unroll
    for (int n = 0; n < 4; ++n) acc[m][n] = (v4i){0, 0, 0, 0};

  const int KSTEPS = K_DIM / BK;  // 64
  for (int kt = 0; kt < KSTEPS; ++kt) {
    __builtin_amdgcn_global_load_lds(
        (const __attribute__((address_space(1))) void*)pA0,
        (__attribute__((address_space(3))) void*)dA0, 16, 0, 0);
    __builtin_amdgcn_global_load_lds(
        (const __attribute__((address_space(1))) void*)pA1,
        (__attribute__((address_space(3))) void*)dA1, 16, 0, 0);
    __builtin_amdgcn_global_load_lds(
        (const __attribute__((address_space(1))) void*)pB0,
        (__attribute__((address_space(3))) void*)dB0, 16, 0, 0);
    __builtin_amdgcn_global_load_lds(
        (const __attribute__((address_space(1))) void*)pB1,
        (__attribute__((address_space(3))) void*)dB1, 16, 0, 0);
    pA0 += BK; pA1 += BK; pB0 += BK; pB1 += BK;

    __syncthreads();  // compiler emits vmcnt(0) drain before barrier

    v4i a[4], b[4];
#pragma unroll
    for (int m = 0; m < 4; ++m) a[m] = *(const v4i*)(lA + aoff[m]);
#pragma unroll
    for (int n = 0; n < 4; ++n) b[n] = *(const v4i*)(lB + boff[n]);

#pragma unroll
    for (int m = 0; m < 4; ++m)
#pragma unroll
      for (int n = 0; n < 4; ++n)
        acc[m][n] = __builtin_amdgcn_mfma_i32_16x16x64_i8(a[m], b[n],
                                                          acc[m][n], 0, 0, 0);

    __syncthreads();
  }

  // ---- epilogue: dequant/requant, write float32 (int8-valued)
  const int orow = row0 + wr * 64;
  const int ocol = col0 + wc * 64;

  float sbv[4];
#pragma unroll
  for (int n = 0; n < 4; ++n) sbv[n] = sB[ocol + n * 16 + fr];

#pragma unroll
  for (int m = 0; m < 4; ++m) {
#pragma unroll
    for (int reg = 0; reg < 4; ++reg) {
      const int grow = orow + m * 16 + fk * 4 + reg;
      const float rA = sA[grow] / sO[grow];
#pragma unroll
      for (int n = 0; n < 4; ++n) {
        float f = rintf(((float)acc[m][n][reg] * rA) * sbv[n]);
        f = fminf(127.0f, fmaxf(-128.0f, f));
        out[(size_t)grow * N_DIM + (ocol + n * 16 + fr)] = f;
      }
    }
  }
}

// ---------------------------------------------------------------------------
// Fallback (only if ws_size too small): correct but slow.
// ---------------------------------------------------------------------------
__global__ void gemm_naive_kernel(const int* __restrict__ A,
                                  const int* __restrict__ B,
                                  const float* __restrict__ sA,
                                  const float* __restrict__ sB,
                                  const float* __restrict__ sO,
                                  float* __restrict__ out) {
  long idx = blockIdx.x * (long)blockDim.x + threadIdx.x;
  if (idx >= (long)M_DIM * N_DIM) return;
  int m = (int)(idx / N_DIM);
  int n = (int)(idx % N_DIM);
  const int4* a = (const int4*)(A + (size_t)m * K_DIM);
  const int4* b = (const int4*)(B + (size_t)n * K_DIM);
  int acc = 0;
  for (int k = 0; k < K_DIM / 4; ++k) {
    int4 x = a[k], y = b[k];
    acc += x.x * y.x + x.y * y.y + x.z * y.z + x.w * y.w;
  }
  float f = rintf((float)acc * (sA[m] / sO[m]) * sB[n]);
  out[idx] = fminf(127.0f, fmaxf(-128.0f, f));
}

__global__ void tail_copy_kernel(const float* __restrict__ scale_out,
                                 float* __restrict__ out_tail) {
  int i = blockIdx.x * blockDim.x + threadIdx.x;
  if (i < M_DIM) out_tail[i] = scale_out[i];
}

// ---------------------------------------------------------------------------
extern "C" void kernel_launch(void* const* d_in, const int* in_sizes, int n_in,
                              void* d_out, int out_size, void* d_ws,
                              size_t ws_size, hipStream_t stream) {
  const int* A = (const int*)d_in[0];
  const float* sA = (const float*)d_in[1];
  const int* B = (const int*)d_in[2];
  const float* sB = (const float*)d_in[3];
  const float* sO = (const float*)d_in[4];
  float* out = (float*)d_out;
  float* out_tail = out + (size_t)M_DIM * N_DIM;

  const size_t need = (size_t)(M_DIM + N_DIM) * K_DIM;  // 50.3 MB of int8
  if (ws_size >= need) {
    int8_t* A8 = (int8_t*)d_ws;
    int8_t* B8 = A8 + (size_t)M_DIM * K_DIM;
    convert_pack_kernel<<<2048, 256, 0, stream>>>(A, B, sO, A8, B8, out_tail);
    gemm_i8_kernel<<<2048, 256, 0, stream>>>(A8, B8, sA, sB, sO, out);
  } else {
    tail_copy_kernel<<<(M_DIM + 255) / 256, 256, 0, stream>>>(sO, out_tail);
    long total = (long)M_DIM * N_DIM;
    int blocks = (int)((total + 255) / 256);
    gemm_naive_kernel<<<blocks, 256, 0, stream>>>(A, B, sA, sB, sO, out);
  }
}

// Round 6
// 395.574 us; speedup vs baseline: 1.1885x; 1.1885x over previous
//
#include <hip/hip_runtime.h>
#include <hip/hip_bf16.h>
#include <stdint.h>

#define M_DIM 8192
#define K_DIM 4096
#define N_DIM 4096
#define NT (K_DIM / 128)  // 32 K-tiles of 128 bytes

typedef int v4i __attribute__((ext_vector_type(4)));

// ---------------------------------------------------------------------------
// Kernel 1: pack int32-stored int8 -> int8 (dense loads/stores), precompute
// sA/sO ratio, copy scale_out to the output tail.
// ---------------------------------------------------------------------------
__global__ void convert_pack_kernel(const int* __restrict__ A,
                                    const int* __restrict__ B,
                                    const float* __restrict__ sA,
                                    const float* __restrict__ sO,
                                    int* __restrict__ A8, int* __restrict__ B8,
                                    float* __restrict__ rAs,
                                    float* __restrict__ out_tail) {
  long gid = blockIdx.x * (long)blockDim.x + threadIdx.x;
  long stride = (long)gridDim.x * blockDim.x;

  for (long i = gid; i < M_DIM; i += stride) {
    float so = sO[i];
    out_tail[i] = so;
    rAs[i] = sA[i] / so;
  }

  const long MK4 = (long)M_DIM * (K_DIM / 4);
  for (long i = gid; i < MK4; i += stride) {
    int4 v = ((const int4*)A)[i];
    A8[i] = (v.x & 255) | ((v.y & 255) << 8) | ((v.z & 255) << 16) |
            ((v.w & 255) << 24);
  }
  const long NK4 = (long)N_DIM * (K_DIM / 4);
  for (long i = gid; i < NK4; i += stride) {
    int4 v = ((const int4*)B)[i];
    B8[i] = (v.x & 255) | ((v.y & 255) << 8) | ((v.z & 255) << 16) |
            ((v.w & 255) << 24);
  }
}

// ---------------------------------------------------------------------------
// Kernel 2: 256x256 8-phase i8 GEMM (T1 XCD swizzle + T2 LDS swizzle +
// T3/T4 8-phase counted-vmcnt + T5 setprio), mfma_i32_16x16x64_i8.
//
// LDS slot (64 KB) layout: [A-h0 16K][A-h1 16K][B-h0 16K][B-h1 16K],
// rows of 128 B stored as 8 granules of 16 B with read swizzle
// chunk' = chunk ^ (row & 7); staging keeps LDS linear and pre-swizzles the
// per-lane GLOBAL source chunk (rule 21: both-sides-or-neither).
// ---------------------------------------------------------------------------
__device__ __forceinline__ void stage_half(const int8_t* g, int8_t* smdst,
                                           int rowoff, int t) {
  const int tt = (t < NT) ? t : (NT - 1);
  const int8_t* s = g + rowoff * K_DIM + tt * 128;
  __builtin_amdgcn_global_load_lds(
      (const __attribute__((address_space(1))) void*)s,
      (__attribute__((address_space(3))) void*)smdst, 16, 0, 0);
  __builtin_amdgcn_global_load_lds(
      (const __attribute__((address_space(1))) void*)(s + 8 * K_DIM),
      (__attribute__((address_space(3))) void*)(smdst + 1024), 16, 0, 0);
}

__device__ __forceinline__ void read_a4(const int8_t* smc, int ar0, int mb,
                                        v4i a[4][2]) {
#pragma unroll
  for (int mm = 0; mm < 4; ++mm) {
    a[mm][0] = *(const v4i*)(smc + (ar0 + (mb + mm) * 2048));
    a[mm][1] = *(const v4i*)(smc + ((ar0 + (mb + mm) * 2048) ^ 64));
  }
}

__device__ __forceinline__ void read_b2(const int8_t* smc, int br0, int nb0,
                                        v4i b[4][2]) {
#pragma unroll
  for (int nn = 0; nn < 2; ++nn) {
    b[nb0 + nn][0] = *(const v4i*)(smc + (br0 + (nb0 + nn) * 2048));
    b[nb0 + nn][1] = *(const v4i*)(smc + ((br0 + (nb0 + nn) * 2048) ^ 64));
  }
}

__device__ __forceinline__ void mfma16(v4i a[4][2], v4i b[4][2], v4i acc[8][4],
                                       int am, int bn) {
#pragma unroll
  for (int s = 0; s < 2; ++s)
#pragma unroll
    for (int mm = 0; mm < 4; ++mm)
#pragma unroll
      for (int nn = 0; nn < 2; ++nn)
        acc[am + mm][bn + nn] = __builtin_amdgcn_mfma_i32_16x16x64_i8(
            a[mm][s], b[bn + nn][s], acc[am + mm][bn + nn], 0, 0, 0);
}

#define BAR() __builtin_amdgcn_s_barrier()
#define LGKM0()                                         \
  {                                                     \
    asm volatile("s_waitcnt lgkmcnt(0)" ::: "memory"); \
    __builtin_amdgcn_sched_barrier(0);                  \
  }
#define VM2() asm volatile("s_waitcnt vmcnt(2)" ::: "memory")
#define SP(x) __builtin_amdgcn_s_setprio(x)

__global__ __launch_bounds__(512) void gemm_i8_8phase(
    const int8_t* __restrict__ A8, const int8_t* __restrict__ B8,
    const float* __restrict__ rAs, const float* __restrict__ sB,
    float* __restrict__ out) {
  __shared__ int8_t sm[2][65536];  // 128 KB: 2 dbuf slots

  const int tid = threadIdx.x;
  const int wid = tid >> 6;
  const int l = tid & 63;

  // T1: XCD-aware bijective swizzle (nwg = 512, divisible by 8)
  const int bid = blockIdx.x;
  const int wg = (bid & 7) * (512 / 8) + (bid >> 3);
  const int tm = wg >> 4;  // 32 row tiles
  const int tn = wg & 15;  // 16 col tiles
  const int row0 = tm * 256;
  const int col0 = tn * 256;

  // staging: per-lane pre-swizzled global base (srcChunk = (j&7)^(j>>3))
  const int srcChunk = ((l & 7) ^ (l >> 3)) << 4;
  const int rowLane = l >> 3;
  const int8_t* gA = A8 + (size_t)(row0 + rowLane) * K_DIM + srcChunk;
  const int8_t* gB = B8 + (size_t)(col0 + rowLane) * K_DIM + srcChunk;

  // fragment read bases (swizzled): chunk'(s) bits01 = fk^(l&3), bit2 = s^((l>>2)&1)
  const int wr = wid >> 2;  // 0..1
  const int wc = wid & 3;   // 0..3
  const int fr = l & 15;
  const int fk = l >> 4;
  const int ar0 = (wr * 128 + fr) * 128 + ((fk ^ (l & 3)) << 4) +
                  (((l >> 2) & 1) << 6);
  const int br0 = 32768 + (wc * 64 + fr) * 128 + ((fk ^ (l & 3)) << 4) +
                  (((l >> 2) & 1) << 6);

  v4i a[4][2], b[4][2];
  v4i acc[8][4];
#pragma unroll
  for (int mm = 0; mm < 8; ++mm)
#pragma unroll
    for (int nn = 0; nn < 4; ++nn) acc[mm][nn] = (v4i){0, 0, 0, 0};

  // ---- prologue: H0-H3 of tile0 (buf0) + H0 of tile1 (buf1)
  {
    int8_t* s0 = (int8_t*)sm[0];
    int8_t* s1 = (int8_t*)sm[1];
    stage_half(gA, s0 + 0 * 16384 + wid * 2048, 0 * 128 + wid * 16, 0);
    stage_half(gA, s0 + 1 * 16384 + wid * 2048, 1 * 128 + wid * 16, 0);
    stage_half(gB, s0 + 2 * 16384 + wid * 2048, 0 * 128 + wid * 16, 0);
    stage_half(gB, s0 + 3 * 16384 + wid * 2048, 1 * 128 + wid * 16, 0);
    stage_half(gA, s1 + 0 * 16384 + wid * 2048, 0 * 128 + wid * 16, 1);
    VM2();
    BAR();
  }

  // ---- main loop: 4 phases per K-tile, stages per tile:
  //   P0: A-h1(T+1)  P1: B-h0(T+1)  P2: B-h1(T+1)  P3: A-h0(T+2) [+vmcnt(2)]
#pragma unroll 2
  for (int T = 0; T < NT; ++T) {
    const int cb = T & 1;
    int8_t* smc = (int8_t*)sm[cb];
    int8_t* smn = (int8_t*)sm[cb ^ 1];

    // P0
    read_a4(smc, ar0, 0, a);
    read_b2(smc, br0, 0, b);
    stage_half(gA, smn + 1 * 16384 + wid * 2048, 1 * 128 + wid * 16, T + 1);
    BAR();
    LGKM0();
    SP(1);
    mfma16(a, b, acc, 0, 0);
    SP(0);
    BAR();

    // P1
    read_b2(smc, br0, 2, b);
    stage_half(gB, smn + 2 * 16384 + wid * 2048, 0 * 128 + wid * 16, T + 1);
    BAR();
    LGKM0();
    SP(1);
    mfma16(a, b, acc, 0, 2);
    SP(0);
    BAR();

    // P2
    read_a4(smc, ar0, 4, a);
    stage_half(gB, smn + 3 * 16384 + wid * 2048, 1 * 128 + wid * 16, T + 1);
    BAR();
    LGKM0();
    SP(1);
    mfma16(a, b, acc, 4, 0);
    SP(0);
    BAR();

    // P3
    stage_half(gA, smc + 0 * 16384 + wid * 2048, 0 * 128 + wid * 16, T + 2);
    VM2();
    BAR();
    SP(1);
    mfma16(a, b, acc, 4, 2);
    SP(0);
    BAR();
  }

  asm volatile("s_waitcnt vmcnt(0)" ::: "memory");

  // ---- epilogue: requant + store float32 (int8-valued)
  const int orow = row0 + wr * 128;
  const int ocol = col0 + wc * 64;
  float sbv[4];
#pragma unroll
  for (int nn = 0; nn < 4; ++nn) sbv[nn] = sB[ocol + nn * 16 + fr];

#pragma unroll
  for (int mm = 0; mm < 8; ++mm) {
#pragma unroll
    for (int reg = 0; reg < 4; ++reg) {
      const int grow = orow + mm * 16 + fk * 4 + reg;
      const float rA = rAs[grow];
      float* op = out + (size_t)grow * N_DIM + ocol + fr;
#pragma unroll
      for (int nn = 0; nn < 4; ++nn) {
        float f = rintf((float)acc[mm][nn][reg] * rA * sbv[nn]);
        f = fminf(127.0f, fmaxf(-128.0f, f));
        op[nn * 16] = f;
      }
    }
  }
}

// ---------------------------------------------------------------------------
// Fallback (ws too small): correct but slow.
// ---------------------------------------------------------------------------
__global__ void gemm_naive_kernel(const int* __restrict__ A,
                                  const int* __restrict__ B,
                                  const float* __restrict__ sA,
                                  const float* __restrict__ sB,
                                  const float* __restrict__ sO,
                                  float* __restrict__ out) {
  long idx = blockIdx.x * (long)blockDim.x + threadIdx.x;
  if (idx >= (long)M_DIM * N_DIM) return;
  int m = (int)(idx / N_DIM);
  int n = (int)(idx % N_DIM);
  const int4* a = (const int4*)(A + (size_t)m * K_DIM);
  const int4* b = (const int4*)(B + (size_t)n * K_DIM);
  int acc = 0;
  for (int k = 0; k < K_DIM / 4; ++k) {
    int4 x = a[k], y = b[k];
    acc += x.x * y.x + x.y * y.y + x.z * y.z + x.w * y.w;
  }
  float f = rintf((float)acc * (sA[m] / sO[m]) * sB[n]);
  out[idx] = fminf(127.0f, fmaxf(-128.0f, f));
}

__global__ void tail_copy_kernel(const float* __restrict__ scale_out,
                                 float* __restrict__ out_tail) {
  int i = blockIdx.x * blockDim.x + threadIdx.x;
  if (i < M_DIM) out_tail[i] = scale_out[i];
}

// ---------------------------------------------------------------------------
extern "C" void kernel_launch(void* const* d_in, const int* in_sizes, int n_in,
                              void* d_out, int out_size, void* d_ws,
                              size_t ws_size, hipStream_t stream) {
  const int* A = (const int*)d_in[0];
  const float* sA = (const float*)d_in[1];
  const int* B = (const int*)d_in[2];
  const float* sB = (const float*)d_in[3];
  const float* sO = (const float*)d_in[4];
  float* out = (float*)d_out;
  float* out_tail = out + (size_t)M_DIM * N_DIM;

  const size_t need = (size_t)(M_DIM + N_DIM) * K_DIM + M_DIM * 4;
  if (ws_size >= need) {
    int8_t* A8 = (int8_t*)d_ws;
    int8_t* B8 = A8 + (size_t)M_DIM * K_DIM;
    float* rAs = (float*)(B8 + (size_t)N_DIM * K_DIM);
    convert_pack_kernel<<<2048, 256, 0, stream>>>(A, B, sA, sO, (int*)A8,
                                                  (int*)B8, rAs, out_tail);
    gemm_i8_8phase<<<512, 512, 0, stream>>>(A8, B8, rAs, sB, out);
  } else {
    tail_copy_kernel<<<(M_DIM + 255) / 256, 256, 0, stream>>>(sO, out_tail);
    long total = (long)M_DIM * N_DIM;
    int blocks = (int)((total + 255) / 256);
    gemm_naive_kernel<<<blocks, 256, 0, stream>>>(A, B, sA, sB, sO, out);
  }
}

// Round 9
// 394.786 us; speedup vs baseline: 1.1908x; 1.0020x over previous
//
#include <hip/hip_runtime.h>
#include <hip/hip_bf16.h>
#include <stdint.h>

#define M_DIM 8192
#define K_DIM 4096
#define N_DIM 4096
#define NT (K_DIM / 128)  // 32 K-tiles of 128 bytes

typedef int v4i __attribute__((ext_vector_type(4)));

// ---------------------------------------------------------------------------
// Kernel 1: pack int32-stored int8 -> int8 (dense loads/stores), precompute
// sA/sO ratio, copy scale_out to the output tail.
// ---------------------------------------------------------------------------
__global__ void convert_pack_kernel(const int* __restrict__ A,
                                    const int* __restrict__ B,
                                    const float* __restrict__ sA,
                                    const float* __restrict__ sO,
                                    int* __restrict__ A8, int* __restrict__ B8,
                                    float* __restrict__ rAs,
                                    float* __restrict__ out_tail) {
  long gid = blockIdx.x * (long)blockDim.x + threadIdx.x;
  long stride = (long)gridDim.x * blockDim.x;

  for (long i = gid; i < M_DIM; i += stride) {
    float so = sO[i];
    out_tail[i] = so;
    rAs[i] = sA[i] / so;
  }

  const long MK4 = (long)M_DIM * (K_DIM / 4);
  for (long i = gid; i < MK4; i += stride) {
    int4 v = ((const int4*)A)[i];
    A8[i] = (v.x & 255) | ((v.y & 255) << 8) | ((v.z & 255) << 16) |
            ((v.w & 255) << 24);
  }
  const long NK4 = (long)N_DIM * (K_DIM / 4);
  for (long i = gid; i < NK4; i += stride) {
    int4 v = ((const int4*)B)[i];
    B8[i] = (v.x & 255) | ((v.y & 255) << 8) | ((v.z & 255) << 16) |
            ((v.w & 255) << 24);
  }
}

// ---------------------------------------------------------------------------
// Kernel 2: 256x256 8-phase i8 GEMM (T1 XCD swizzle + T2 LDS swizzle +
// T3/T4 8-phase counted-vmcnt + T5 setprio), mfma_i32_16x16x64_i8.
//
// r6 change: deepen the staging pipeline. Old per-tile stage schedule
// {P0:A-h1, P1:B-h0, P2:B-h1, P3:A-h0(T+2)} gave the youngest half (B-h1)
// only 1 phase of flight before the P3 vmcnt drain (~650 cyc < HBM 900).
// New schedule {P0:A-h1+B-h0, P1:B-h1, P2:-, P3:A-h0(T+2)} gives youngest
// drained half 2 phases (~1300 cyc) and oldest 4.
// ---------------------------------------------------------------------------
__device__ __forceinline__ void stage_half(const int8_t* g, int8_t* smdst,
                                           int rowoff, int t) {
  const int tt = (t < NT) ? t : (NT - 1);
  const int8_t* s = g + rowoff * K_DIM + tt * 128;
  __builtin_amdgcn_global_load_lds(
      (const __attribute__((address_space(1))) void*)s,
      (__attribute__((address_space(3))) void*)smdst, 16, 0, 0);
  __builtin_amdgcn_global_load_lds(
      (const __attribute__((address_space(1))) void*)(s + 8 * K_DIM),
      (__attribute__((address_space(3))) void*)(smdst + 1024), 16, 0, 0);
}

__device__ __forceinline__ void read_a4(const int8_t* smc, int ar0, int mb,
                                        v4i a[4][2]) {
#pragma unroll
  for (int mm = 0; mm < 4; ++mm) {
    a[mm][0] = *(const v4i*)(smc + (ar0 + (mb + mm) * 2048));
    a[mm][1] = *(const v4i*)(smc + ((ar0 + (mb + mm) * 2048) ^ 64));
  }
}

__device__ __forceinline__ void read_b2(const int8_t* smc, int br0, int nb0,
                                        v4i b[4][2]) {
#pragma unroll
  for (int nn = 0; nn < 2; ++nn) {
    b[nb0 + nn][0] = *(const v4i*)(smc + (br0 + (nb0 + nn) * 2048));
    b[nb0 + nn][1] = *(const v4i*)(smc + ((br0 + (nb0 + nn) * 2048) ^ 64));
  }
}

__device__ __forceinline__ void mfma16(v4i a[4][2], v4i b[4][2], v4i acc[8][4],
                                       int am, int bn) {
#pragma unroll
  for (int s = 0; s < 2; ++s)
#pragma unroll
    for (int mm = 0; mm < 4; ++mm)
#pragma unroll
      for (int nn = 0; nn < 2; ++nn)
        acc[am + mm][bn + nn] = __builtin_amdgcn_mfma_i32_16x16x64_i8(
            a[mm][s], b[bn + nn][s], acc[am + mm][bn + nn], 0, 0, 0);
}

#define BAR() __builtin_amdgcn_s_barrier()
#define LGKM0()                                         \
  {                                                     \
    asm volatile("s_waitcnt lgkmcnt(0)" ::: "memory"); \
    __builtin_amdgcn_sched_barrier(0);                  \
  }
#define VM2() asm volatile("s_waitcnt vmcnt(2)" ::: "memory")
#define SP(x) __builtin_amdgcn_s_setprio(x)

__global__ __launch_bounds__(512) void gemm_i8_8phase(
    const int8_t* __restrict__ A8, const int8_t* __restrict__ B8,
    const float* __restrict__ rAs, const float* __restrict__ sB,
    float* __restrict__ out) {
  __shared__ int8_t sm[2][65536];  // 128 KB: 2 dbuf slots

  const int tid = threadIdx.x;
  const int wid = tid >> 6;
  const int l = tid & 63;

  // T1: XCD-aware bijective swizzle (nwg = 512, divisible by 8)
  const int bid = blockIdx.x;
  const int wg = (bid & 7) * (512 / 8) + (bid >> 3);
  const int tm = wg >> 4;  // 32 row tiles
  const int tn = wg & 15;  // 16 col tiles
  const int row0 = tm * 256;
  const int col0 = tn * 256;

  // staging: per-lane pre-swizzled global base (srcChunk = (j&7)^(j>>3))
  const int srcChunk = ((l & 7) ^ (l >> 3)) << 4;
  const int rowLane = l >> 3;
  const int8_t* gA = A8 + (size_t)(row0 + rowLane) * K_DIM + srcChunk;
  const int8_t* gB = B8 + (size_t)(col0 + rowLane) * K_DIM + srcChunk;

  // fragment read bases (swizzled): chunk'(s) bits01 = fk^(l&3), bit2 = s^((l>>2)&1)
  const int wr = wid >> 2;  // 0..1
  const int wc = wid & 3;   // 0..3
  const int fr = l & 15;
  const int fk = l >> 4;
  const int ar0 = (wr * 128 + fr) * 128 + ((fk ^ (l & 3)) << 4) +
                  (((l >> 2) & 1) << 6);
  const int br0 = 32768 + (wc * 64 + fr) * 128 + ((fk ^ (l & 3)) << 4) +
                  (((l >> 2) & 1) << 6);

  v4i a[4][2], b[4][2];
  v4i acc[8][4];
#pragma unroll
  for (int mm = 0; mm < 8; ++mm)
#pragma unroll
    for (int nn = 0; nn < 4; ++nn) acc[mm][nn] = (v4i){0, 0, 0, 0};

  // ---- prologue: H0-H3 of tile0 (buf0) + A-h0 of tile1 (buf1)
  {
    int8_t* s0 = (int8_t*)sm[0];
    int8_t* s1 = (int8_t*)sm[1];
    stage_half(gA, s0 + 0 * 16384 + wid * 2048, 0 * 128 + wid * 16, 0);
    stage_half(gA, s0 + 1 * 16384 + wid * 2048, 1 * 128 + wid * 16, 0);
    stage_half(gB, s0 + 2 * 16384 + wid * 2048, 0 * 128 + wid * 16, 0);
    stage_half(gB, s0 + 3 * 16384 + wid * 2048, 1 * 128 + wid * 16, 0);
    stage_half(gA, s1 + 0 * 16384 + wid * 2048, 0 * 128 + wid * 16, 1);
    VM2();
    BAR();
  }

  // ---- main loop: 4 phases per K-tile, stage schedule (r6):
  //   P0: A-h1(T+1)+B-h0(T+1)  P1: B-h1(T+1)  P2: -  P3: A-h0(T+2) [+vmcnt(2)]
#pragma unroll 2
  for (int T = 0; T < NT; ++T) {
    const int cb = T & 1;
    int8_t* smc = (int8_t*)sm[cb];
    int8_t* smn = (int8_t*)sm[cb ^ 1];

    // P0
    read_a4(smc, ar0, 0, a);
    read_b2(smc, br0, 0, b);
    stage_half(gA, smn + 1 * 16384 + wid * 2048, 1 * 128 + wid * 16, T + 1);
    stage_half(gB, smn + 2 * 16384 + wid * 2048, 0 * 128 + wid * 16, T + 1);
    BAR();
    LGKM0();
    SP(1);
    mfma16(a, b, acc, 0, 0);
    SP(0);
    BAR();

    // P1
    read_b2(smc, br0, 2, b);
    stage_half(gB, smn + 3 * 16384 + wid * 2048, 1 * 128 + wid * 16, T + 1);
    BAR();
    LGKM0();
    SP(1);
    mfma16(a, b, acc, 0, 2);
    SP(0);
    BAR();

    // P2
    read_a4(smc, ar0, 4, a);
    BAR();
    LGKM0();
    SP(1);
    mfma16(a, b, acc, 4, 0);
    SP(0);
    BAR();

    // P3
    stage_half(gA, smc + 0 * 16384 + wid * 2048, 0 * 128 + wid * 16, T + 2);
    VM2();
    BAR();
    SP(1);
    mfma16(a, b, acc, 4, 2);
    SP(0);
    BAR();
  }

  asm volatile("s_waitcnt vmcnt(0)" ::: "memory");

  // ---- epilogue: requant + store float32 (int8-valued)
  const int orow = row0 + wr * 128;
  const int ocol = col0 + wc * 64;
  float sbv[4];
#pragma unroll
  for (int nn = 0; nn < 4; ++nn) sbv[nn] = sB[ocol + nn * 16 + fr];

#pragma unroll
  for (int mm = 0; mm < 8; ++mm) {
#pragma unroll
    for (int reg = 0; reg < 4; ++reg) {
      const int grow = orow + mm * 16 + fk * 4 + reg;
      const float rA = rAs[grow];
      float* op = out + (size_t)grow * N_DIM + ocol + fr;
#pragma unroll
      for (int nn = 0; nn < 4; ++nn) {
        float f = rintf((float)acc[mm][nn][reg] * rA * sbv[nn]);
        f = fminf(127.0f, fmaxf(-128.0f, f));
        op[nn * 16] = f;
      }
    }
  }
}

// ---------------------------------------------------------------------------
// Fallback (ws too small): correct but slow.
// ---------------------------------------------------------------------------
__global__ void gemm_naive_kernel(const int* __restrict__ A,
                                  const int* __restrict__ B,
                                  const float* __restrict__ sA,
                                  const float* __restrict__ sB,
                                  const float* __restrict__ sO,
                                  float* __restrict__ out) {
  long idx = blockIdx.x * (long)blockDim.x + threadIdx.x;
  if (idx >= (long)M_DIM * N_DIM) return;
  int m = (int)(idx / N_DIM);
  int n = (int)(idx % N_DIM);
  const int4* a = (const int4*)(A + (size_t)m * K_DIM);
  const int4* b = (const int4*)(B + (size_t)n * K_DIM);
  int acc = 0;
  for (int k = 0; k < K_DIM / 4; ++k) {
    int4 x = a[k], y = b[k];
    acc += x.x * y.x + x.y * y.y + x.z * y.z + x.w * y.w;
  }
  float f = rintf((float)acc * (sA[m] / sO[m]) * sB[n]);
  out[idx] = fminf(127.0f, fmaxf(-128.0f, f));
}

__global__ void tail_copy_kernel(const float* __restrict__ scale_out,
                                 float* __restrict__ out_tail) {
  int i = blockIdx.x * blockDim.x + threadIdx.x;
  if (i < M_DIM) out_tail[i] = scale_out[i];
}

// ---------------------------------------------------------------------------
extern "C" void kernel_launch(void* const* d_in, const int* in_sizes, int n_in,
                              void* d_out, int out_size, void* d_ws,
                              size_t ws_size, hipStream_t stream) {
  const int* A = (const int*)d_in[0];
  const float* sA = (const float*)d_in[1];
  const int* B = (const int*)d_in[2];
  const float* sB = (const float*)d_in[3];
  const float* sO = (const float*)d_in[4];
  float* out = (float*)d_out;
  float* out_tail = out + (size_t)M_DIM * N_DIM;

  const size_t need = (size_t)(M_DIM + N_DIM) * K_DIM + M_DIM * 4;
  if (ws_size >= need) {
    int8_t* A8 = (int8_t*)d_ws;
    int8_t* B8 = A8 + (size_t)M_DIM * K_DIM;
    float* rAs = (float*)(B8 + (size_t)N_DIM * K_DIM);
    convert_pack_kernel<<<2048, 256, 0, stream>>>(A, B, sA, sO, (int*)A8,
                                                  (int*)B8, rAs, out_tail);
    gemm_i8_8phase<<<512, 512, 0, stream>>>(A8, B8, rAs, sB, out);
  } else {
    tail_copy_kernel<<<(M_DIM + 255) / 256, 256, 0, stream>>>(sO, out_tail);
    long total = (long)M_DIM * N_DIM;
    int blocks = (int)((total + 255) / 256);
    gemm_naive_kernel<<<blocks, 256, 0, stream>>>(A, B, sA, sB, sO, out);
  }
}